// Round 5
// baseline (220.455 us; speedup 1.0000x reference)
//
#include <hip/hip_runtime.h>
#include <math.h>

#define NN 50000
#define NE 600000
#define NP 200000
#define NB_SCAN 49       // ceil(NN / 1024)
#define NPART 8          // XCD count
#define PART_N (NN / NPART)       // 6250 nodes per partition
#define FILL_CHUNKS 75
#define CHUNK_E (NE / FILL_CHUNKS)  // 8000 edges per chunk (divisible by 4)

typedef unsigned int uint;
typedef unsigned short ushort;
typedef __attribute__((ext_vector_type(8))) short bf16x8;
typedef __attribute__((ext_vector_type(4))) float f32x4;

// ---- bf16 helpers (RNE) ----
__device__ __forceinline__ ushort f2bf(float f) {
    uint u = __float_as_uint(f);
    uint r = (u + 0x7FFFu + ((u >> 16) & 1u)) >> 16;
    return (ushort)r;
}
__device__ __forceinline__ float bf2f(uint lo16) {
    return __uint_as_float(lo16 << 16);
}

__device__ __forceinline__ int wave_iscan(int v, int lane) {
#pragma unroll
    for (int off = 1; off < 64; off <<= 1) {
        int t = __shfl_up(v, off, 64);
        if (lane >= off) v += t;
    }
    return v;
}

// async global->LDS, 16B per lane; dest = uniform base + lane*16 (m104 contract)
typedef const __attribute__((address_space(1))) uint* gas_ptr;
typedef __attribute__((address_space(3))) uint* las_ptr;
__device__ __forceinline__ void gload_lds16(const uint* g, uint* l) {
    __builtin_amdgcn_global_load_lds((gas_ptr)(void*)g, (las_ptr)(void*)l, 16, 0, 0);
}

// accumulate 8 bf16 (uint4) into f32[8]
__device__ __forceinline__ void acc8(float* a, uint4 v) {
    a[0] += bf2f(v.x & 0xffffu); a[1] += bf2f(v.x >> 16);
    a[2] += bf2f(v.y & 0xffffu); a[3] += bf2f(v.y >> 16);
    a[4] += bf2f(v.z & 0xffffu); a[5] += bf2f(v.z >> 16);
    a[6] += bf2f(v.w & 0xffffu); a[7] += bf2f(v.w >> 16);
}

// ---- W swizzle into MFMA B-operand layout (bf16) ----
// Bp[((ct*(N/16)+nt)*64 + lane)*8 + j] = Wcat[ct*32 + (lane>>4)*8 + j][nt*16 + (lane&15)]
template <int K, int N>
__device__ __forceinline__ void prepB_one(int idx, const float* __restrict__ Wt,
                                          const float* __restrict__ Wb,
                                          ushort* __restrict__ Bp) {
    int lane = idx & 63;
    int nt = (idx >> 6) % (N / 16);
    int ct = idx / (64 * (N / 16));
    int n = nt * 16 + (lane & 15);
    int kb = ct * 32 + (lane >> 4) * 8;
#pragma unroll
    for (int j = 0; j < 8; j++) {
        int k = kb + j;
        float w = (k < K / 2) ? Wt[(size_t)k * N + n] : Wb[(size_t)(k - K / 2) * N + n];
        Bp[(size_t)idx * 8 + j] = f2bf(w);
    }
}

// ---------------- fused prologue ----------------
// ranges: x->bf16 compact (float4) | deg histogram | Bp1 swizzle | pq vectors | cab scalars
// pq[0:256]=W2l@wa, pq[256:512]=W2l@wb, pq[512:768]=W2r@wa, pq[768:1024]=W2r@wb
#define T_PREP (NN * 32)
#define T_DEG  (T_PREP + NE)
#define T_B1   (T_DEG + 8192)
#define T_PQ   (T_B1 + 1024)
#define T_CAB  (T_PQ + 2)
__global__ void k_pre(const float* __restrict__ x, uint* __restrict__ xb,
                      const int* __restrict__ dst, int* __restrict__ deg,
                      const float* __restrict__ W1l, const float* __restrict__ W1r,
                      ushort* __restrict__ Bp1,
                      const float* __restrict__ W2l, const float* __restrict__ W2r,
                      const float* __restrict__ Wlin, const float* __restrict__ b2l,
                      float* __restrict__ pq, float* __restrict__ cab) {
    int t = blockIdx.x * 256 + threadIdx.x;
    if (t < T_PREP) {
        int n = t >> 5, c4 = t & 31;
        float4 v = *(const float4*)(x + (size_t)n * 128 + c4 * 4);
        uint2 o;
        o.x = (uint)f2bf(v.x) | ((uint)f2bf(v.y) << 16);
        o.y = (uint)f2bf(v.z) | ((uint)f2bf(v.w) << 16);
        *(uint2*)(xb + (size_t)n * 64 + c4 * 2) = o;  // compact bf16 x rows (256 B)
    } else if (t < T_DEG) {
        atomicAdd(deg + dst[t - T_PREP], 1);
    } else if (t < T_B1) {
        prepB_one<256, 256>(t - T_DEG, W1l, W1r, Bp1);
    } else if (t < T_PQ) {
        int idx = t - T_B1;
        int vec = idx >> 8;          // 0..3
        int k = idx & 255;
        const float* W = (vec < 2) ? W2l : W2r;    // [256,128]
        const float* wl = Wlin + (vec & 1) * 128;  // wa or wb
        float s = 0.f;
#pragma unroll 4
        for (int j = 0; j < 128; j++) s += W[(size_t)k * 128 + j] * wl[j];
        pq[idx] = s;
    } else if (t < T_CAB) {
        int i = t - T_PQ;
        float s = 0.f;
        for (int j = 0; j < 128; j++) s += b2l[j] * Wlin[i * 128 + j];
        cab[i] = s;
    }
}

// ---------------- fused scan (one launch, 49 co-resident blocks) ----------------------
__global__ __launch_bounds__(1024) void k_scan(const int* __restrict__ deg,
                                               int* __restrict__ bsum,
                                               int* __restrict__ flags,
                                               int* __restrict__ rowptr,
                                               int* __restrict__ cursor) {
    int tid = threadIdx.x;
    int i = blockIdx.x * 1024 + tid;
    int lane = tid & 63, wid = tid >> 6;
    int v = (i < NN) ? deg[i] : 0;
    int incl = wave_iscan(v, lane);
    __shared__ int wt[16];
    __shared__ int sboff;
    if (lane == 63) wt[wid] = incl;
    __syncthreads();
    if (tid < 16) {
        int w = wt[tid];
#pragma unroll
        for (int off = 1; off < 16; off <<= 1) {
            int t = __shfl_up(w, off, 64);
            if (tid >= off) w += t;
        }
        wt[tid] = w;
    }
    __syncthreads();
    int base = (wid > 0) ? wt[wid - 1] : 0;
    int excl_local = incl - v + base;  // exclusive within block (register only)
    if (tid == 0)
        __hip_atomic_store(&bsum[blockIdx.x], wt[15], __ATOMIC_RELEASE,
                           __HIP_MEMORY_SCOPE_AGENT);
    // ---- grid barrier ----
    __syncthreads();
    if (tid == 0) {
        __hip_atomic_fetch_add(&flags[0], 1, __ATOMIC_ACQ_REL, __HIP_MEMORY_SCOPE_AGENT);
        while (__hip_atomic_load(&flags[0], __ATOMIC_ACQUIRE,
                                 __HIP_MEMORY_SCOPE_AGENT) < NB_SCAN) {}
    }
    __syncthreads();
    // ---- block offset = sum of bsum for blocks before me ----
    if (tid < 64) {
        int b = (tid < NB_SCAN && tid < (int)blockIdx.x)
                    ? __hip_atomic_load(&bsum[tid], __ATOMIC_ACQUIRE,
                                        __HIP_MEMORY_SCOPE_AGENT)
                    : 0;
#pragma unroll
        for (int off = 1; off < 64; off <<= 1) b += __shfl_xor(b, off, 64);
        if (tid == 0) sboff = b;
    }
    __syncthreads();
    int boff = sboff;
    if (i < NN) {
        int rv = excl_local + boff;
        rowptr[i] = rv;
        cursor[i] = rv;
    }
    if (i == 0) rowptr[NN] = NE;
}

// ---------------- XCD-partitioned edge placement --------------------------------------
// Block b scans edge chunk (b>>3) but only places edges with dst in node partition
// (b&7). blockIdx%8 == XCD id (round-robin dispatch), so each cursor/ssrc line is
// touched by exactly ONE XCD's L2: atomics are L2-local, no cross-XCD line ping-pong.
// Cost: 8x redundant read of dst/src chunks (read-only, L2-replicated -> cheap).
__global__ void k_fill(const int* __restrict__ src, const int* __restrict__ dst,
                       int* __restrict__ cursor, int* __restrict__ ssrc) {
    int part = blockIdx.x & 7;
    int chunk = blockIdx.x >> 3;
    int lo = part * PART_N;
    int e_begin = chunk * CHUNK_E;
    int e_end = e_begin + CHUNK_E;
    for (int e0 = e_begin + threadIdx.x * 4; e0 < e_end; e0 += 1024) {
        int4 d4 = *(const int4*)(dst + e0);
        int4 s4 = *(const int4*)(src + e0);
        if ((uint)(d4.x - lo) < (uint)PART_N) ssrc[atomicAdd(cursor + d4.x, 1)] = s4.x;
        if ((uint)(d4.y - lo) < (uint)PART_N) ssrc[atomicAdd(cursor + d4.y, 1)] = s4.y;
        if ((uint)(d4.z - lo) < (uint)PART_N) ssrc[atomicAdd(cursor + d4.z, 1)] = s4.z;
        if ((uint)(d4.w - lo) < (uint)PART_N) ssrc[atomicAdd(cursor + d4.w, 1)] = s4.w;
    }
}

// ---------------- gather-mean of x(bf16) -> agg (compact) -----------------------------
// Wave per node (max TLP for the latency-bound random gather); 16 lanes x uint4 per row.
// Main loop: 16 edges with 4 index + 4 data loads in flight; then 8/4/tail.
__global__ void k_agg1(const uint* __restrict__ xb, uint* __restrict__ aggb,
                       const int* __restrict__ rowptr, const int* __restrict__ ssrc) {
    int t = blockIdx.x * 256 + threadIdx.x;
    int n = t >> 6;
    if (n >= NN) return;
    int lane = t & 63;
    int g = lane >> 4;      // edge group 0..3
    int s = lane & 15;      // 16-byte chunk within row (cols 8s..8s+7)
    int r0 = rowptr[n], r1 = rowptr[n + 1];
    float a0[8] = {0.f, 0.f, 0.f, 0.f, 0.f, 0.f, 0.f, 0.f};
    float a1[8] = {0.f, 0.f, 0.f, 0.f, 0.f, 0.f, 0.f, 0.f};
    int e = r0;
    for (; e + 16 <= r1; e += 16) {
        int i0 = ssrc[e + g];
        int i1 = ssrc[e + 4 + g];
        int i2 = ssrc[e + 8 + g];
        int i3 = ssrc[e + 12 + g];
        uint4 v0 = *(const uint4*)(xb + (size_t)i0 * 64 + s * 4);
        uint4 v1 = *(const uint4*)(xb + (size_t)i1 * 64 + s * 4);
        uint4 v2 = *(const uint4*)(xb + (size_t)i2 * 64 + s * 4);
        uint4 v3 = *(const uint4*)(xb + (size_t)i3 * 64 + s * 4);
        acc8(a0, v0); acc8(a1, v1); acc8(a0, v2); acc8(a1, v3);
    }
    if (e + 8 <= r1) {
        int i0 = ssrc[e + g];
        int i1 = ssrc[e + 4 + g];
        uint4 v0 = *(const uint4*)(xb + (size_t)i0 * 64 + s * 4);
        uint4 v1 = *(const uint4*)(xb + (size_t)i1 * 64 + s * 4);
        acc8(a0, v0); acc8(a1, v1);
        e += 8;
    }
    if (e + 4 <= r1) {
        int i0 = ssrc[e + g];
        uint4 v0 = *(const uint4*)(xb + (size_t)i0 * 64 + s * 4);
        acc8(a0, v0);
        e += 4;
    }
    int rem = r1 - e;  // 0..3
    if (g < rem) {
        int i0 = ssrc[e + g];
        uint4 v0 = *(const uint4*)(xb + (size_t)i0 * 64 + s * 4);
        acc8(a1, v0);
    }
    float ax[8];
#pragma unroll
    for (int j = 0; j < 8; j++) ax[j] = a0[j] + a1[j];
    // fold the 4 edge-groups (lanes differing in bits 4,5 hold same cols)
#pragma unroll
    for (int j = 0; j < 8; j++) {
        ax[j] += __shfl_xor(ax[j], 16, 64);
        ax[j] += __shfl_xor(ax[j], 32, 64);
    }
    if (g == 0) {
        float sc = 1.0f / fmaxf((float)(r1 - r0), 1.0f);
        uint4 o;
        o.x = (uint)f2bf(ax[0] * sc) | ((uint)f2bf(ax[1] * sc) << 16);
        o.y = (uint)f2bf(ax[2] * sc) | ((uint)f2bf(ax[3] * sc) << 16);
        o.z = (uint)f2bf(ax[4] * sc) | ((uint)f2bf(ax[5] * sc) << 16);
        o.w = (uint)f2bf(ax[6] * sc) | ((uint)f2bf(ax[7] * sc) << 16);
        *(uint4*)(aggb + (size_t)n * 64 + s * 4) = o;
    }
}

// ---------------- layer-1 GEMM + fused layer-2 projection -----------------------------
// 64-row tiles: A (64 rows x 256 K) staged ONCE per block into LDS via global_load_lds
// in fragment-linear layout: chunk (rt,ct) at byte chunk*1024 + lane*16 holds row
// (rt*16 + l15), K-cols ct*32 + quad*8 .. +7. Every ds_read_b128 lane-linear -> 0
// conflicts. 128 MFMA per wave per staging barrier (2x round-4 intensity).
// Layouts (m89/m91-verified): A-frag A[m=lane&15][k=quad*8+j]; C/D col=lane&15, row=quad*4+reg.
__global__ __launch_bounds__(256) void k_gemm1(const uint* __restrict__ agg,
                                               const uint* __restrict__ xbu,
                                               const ushort* __restrict__ Bp,
                                               const float* __restrict__ bias,
                                               const float* __restrict__ pq,
                                               float2* __restrict__ g2,
                                               float2* __restrict__ u2) {
    __shared__ uint Af[32 * 256];   // 32 chunks x 1 KB = 32 KB
    __shared__ float red[4][4][64]; // 4 KB
    const int NTW = 4;
    int wave = threadIdx.x >> 6;
    int lane = threadIdx.x & 63;
    int quad = lane >> 4;
    int l15 = lane & 15;
    int mbase = blockIdx.x * 64;

    // ---- stage A: 32 chunks, 8 per wave; per-lane global src, lane-linear LDS dest
#pragma unroll
    for (int i = 0; i < 8; i++) {
        int chunk = wave * 8 + i;        // 0..31
        int rt = chunk >> 3;             // row tile 0..3
        int ct = chunk & 7;              // K tile 0..7
        int node = mbase + rt * 16 + l15;
        if (node >= NN) node = NN - 1;
        const uint* srcp = ((ct < 4) ? agg : xbu)
                           + (size_t)node * 64 + (ct & 3) * 16 + quad * 4;
        gload_lds16(srcp, &Af[chunk * 256 + lane * 4]);
    }
    __syncthreads();  // drains vmcnt for global_load_lds + block barrier

    f32x4 acc[4][NTW];
#pragma unroll
    for (int rt = 0; rt < 4; rt++)
#pragma unroll
        for (int i = 0; i < NTW; i++) acc[rt][i] = (f32x4){0.f, 0.f, 0.f, 0.f};
    const bf16x8* bp = (const bf16x8*)Bp;
#pragma unroll
    for (int ct = 0; ct < 8; ct++) {
        bf16x8 a0 = *(const bf16x8*)(&Af[(0 * 8 + ct) * 256 + lane * 4]);
        bf16x8 a1 = *(const bf16x8*)(&Af[(1 * 8 + ct) * 256 + lane * 4]);
        bf16x8 a2 = *(const bf16x8*)(&Af[(2 * 8 + ct) * 256 + lane * 4]);
        bf16x8 a3 = *(const bf16x8*)(&Af[(3 * 8 + ct) * 256 + lane * 4]);
#pragma unroll
        for (int ntl = 0; ntl < NTW; ntl++) {
            int nt = wave * NTW + ntl;
            bf16x8 b = bp[(ct * 16 + nt) * 64 + lane];
            acc[0][ntl] = __builtin_amdgcn_mfma_f32_16x16x32_bf16(a0, b, acc[0][ntl], 0, 0, 0);
            acc[1][ntl] = __builtin_amdgcn_mfma_f32_16x16x32_bf16(a1, b, acc[1][ntl], 0, 0, 0);
            acc[2][ntl] = __builtin_amdgcn_mfma_f32_16x16x32_bf16(a2, b, acc[2][ntl], 0, 0, 0);
            acc[3][ntl] = __builtin_amdgcn_mfma_f32_16x16x32_bf16(a3, b, acc[3][ntl], 0, 0, 0);
        }
    }
    // epilogue: relu + project onto pq
    float pga[4][4], pgb[4][4], pua[4][4], pub[4][4];
#pragma unroll
    for (int rt = 0; rt < 4; rt++)
#pragma unroll
        for (int reg = 0; reg < 4; reg++) {
            pga[rt][reg] = 0.f; pgb[rt][reg] = 0.f;
            pua[rt][reg] = 0.f; pub[rt][reg] = 0.f;
        }
#pragma unroll
    for (int ntl = 0; ntl < NTW; ntl++) {
        int col = (wave * NTW + ntl) * 16 + l15;
        float bv = bias[col];
        float wpa = pq[col], wpb = pq[256 + col];
        float wqa = pq[512 + col], wqb = pq[768 + col];
#pragma unroll
        for (int rt = 0; rt < 4; rt++) {
#pragma unroll
            for (int reg = 0; reg < 4; reg++) {
                float v = acc[rt][ntl][reg] + bv;
                v = v > 0.f ? v : 0.f;
                pga[rt][reg] += v * wpa;  pgb[rt][reg] += v * wpb;
                pua[rt][reg] += v * wqa;  pub[rt][reg] += v * wqb;
            }
        }
    }
#pragma unroll
    for (int off = 1; off < 16; off <<= 1) {
#pragma unroll
        for (int rt = 0; rt < 4; rt++) {
#pragma unroll
            for (int reg = 0; reg < 4; reg++) {
                pga[rt][reg] += __shfl_xor(pga[rt][reg], off, 64);
                pgb[rt][reg] += __shfl_xor(pgb[rt][reg], off, 64);
                pua[rt][reg] += __shfl_xor(pua[rt][reg], off, 64);
                pub[rt][reg] += __shfl_xor(pub[rt][reg], off, 64);
            }
        }
    }
    if (l15 == 0) {
#pragma unroll
        for (int rt = 0; rt < 4; rt++) {
#pragma unroll
            for (int reg = 0; reg < 4; reg++) {
                int row = rt * 16 + quad * 4 + reg;
                red[0][wave][row] = pga[rt][reg];
                red[1][wave][row] = pgb[rt][reg];
                red[2][wave][row] = pua[rt][reg];
                red[3][wave][row] = pub[rt][reg];
            }
        }
    }
    __syncthreads();
    if (threadIdx.x < 64) {
        int row = threadIdx.x;
        int m = mbase + row;
        if (m < NN) {
            float ga = (red[0][0][row] + red[0][1][row]) + (red[0][2][row] + red[0][3][row]);
            float gb = (red[1][0][row] + red[1][1][row]) + (red[1][2][row] + red[1][3][row]);
            float ua = (red[2][0][row] + red[2][1][row]) + (red[2][2][row] + red[2][3][row]);
            float ub = (red[3][0][row] + red[3][1][row]) + (red[3][2][row] + red[3][3][row]);
            g2[m] = make_float2(ga, gb);
            u2[m] = make_float2(ua, ub);
        }
    }
}

// ---------------- scalar gather-mean + final add: sa/sb per node ----------------------
__global__ void k_sagg(const float2* __restrict__ g2, const float2* __restrict__ u2,
                       const int* __restrict__ rowptr, const int* __restrict__ ssrc,
                       const float* __restrict__ cab,
                       float* __restrict__ sa, float* __restrict__ sb) {
    int n = blockIdx.x * 256 + threadIdx.x;
    if (n >= NN) return;
    int r0 = rowptr[n], r1 = rowptr[n + 1];
    float a0 = 0.f, b0 = 0.f, a1 = 0.f, b1 = 0.f;
    float a2 = 0.f, b2 = 0.f, a3 = 0.f, b3 = 0.f;
    int e = r0;
    for (; e + 4 <= r1; e += 4) {
        float2 v0 = g2[ssrc[e]];
        float2 v1 = g2[ssrc[e + 1]];
        float2 v2 = g2[ssrc[e + 2]];
        float2 v3 = g2[ssrc[e + 3]];
        a0 += v0.x; b0 += v0.y;
        a1 += v1.x; b1 += v1.y;
        a2 += v2.x; b2 += v2.y;
        a3 += v3.x; b3 += v3.y;
    }
    for (; e < r1; e++) {
        float2 v = g2[ssrc[e]];
        a0 += v.x; b0 += v.y;
    }
    float sc = 1.0f / fmaxf((float)(r1 - r0), 1.0f);
    float2 u = u2[n];
    sa[n] = ((a0 + a1) + (a2 + a3)) * sc + u.x + cab[0];
    sb[n] = ((b0 + b1) + (b2 + b3)) * sc + u.y + cab[1];
}

// ---------------- pair scorer: out[p] = sigmoid(sa[a] + sb[b] + blin) ----------------
__global__ void k_pairs(const float* __restrict__ sa, const float* __restrict__ sb,
                        const int* __restrict__ mask, const float* __restrict__ blin,
                        float* __restrict__ out) {
    int p = blockIdx.x * 256 + threadIdx.x;
    if (p >= NP) return;
    int2 m = ((const int2*)mask)[p];
    float v = sa[m.x] + sb[m.y] + blin[0];
    out[p] = 1.0f / (1.0f + __expf(-v));
}

extern "C" void kernel_launch(void* const* d_in, const int* in_sizes, int n_in,
                              void* d_out, int out_size, void* d_ws, size_t ws_size,
                              hipStream_t stream) {
    const float* x    = (const float*)d_in[0];   // [50000,128]
    const int*   ei   = (const int*)  d_in[1];   // [2,600000]
    const int*   mask = (const int*)  d_in[2];   // [200000,2]
    const float* W1l  = (const float*)d_in[3];   // [128,256]
    const float* b1l  = (const float*)d_in[4];   // [256]
    const float* W1r  = (const float*)d_in[5];   // [128,256]
    const float* W2l  = (const float*)d_in[6];   // [256,128]
    const float* b2l  = (const float*)d_in[7];   // [128]
    const float* W2r  = (const float*)d_in[8];   // [256,128]
    const float* Wlin = (const float*)d_in[9];   // [256,1]
    const float* blin = (const float*)d_in[10];  // [1]
    float* out = (float*)d_out;                  // [200000,1]

    const int* src = ei;
    const int* dst = ei + NE;

    char* ws = (char*)d_ws;
    int*    deg    = (int*)(ws);                             // 200 KB
    int*    flags  = (int*)(ws + 0xF0000);                   // 2 ints, zeroed w/ deg
    int*    rowptr = (int*)(ws + (size_t)1 * (1 << 20));
    int*    cursor = (int*)(ws + (size_t)2 * (1 << 20));
    int*    ssrc   = (int*)(ws + (size_t)3 * (1 << 20));     // 2.4 MB
    int*    bsum   = (int*)(ws + (size_t)6 * (1 << 20));     // 196 B
    ushort* Bp1    = (ushort*)(ws + (size_t)8 * (1 << 20));  // 128 KB
    float*  pq     = (float*)(ws + (size_t)9 * (1 << 20));   // 4 KB
    float*  cab    = (float*)(ws + (size_t)9 * (1 << 20) + 65536);
    float*  sa     = (float*)(ws + (size_t)10 * (1 << 20));  // 200 KB
    float*  sb     = (float*)(ws + (size_t)11 * (1 << 20));  // 200 KB
    float2* g2     = (float2*)(ws + (size_t)12 * (1 << 20)); // 400 KB
    float2* u2     = (float2*)(ws + (size_t)13 * (1 << 20)); // 400 KB
    uint*   xb     = (uint*)(ws + (size_t)14 * (1 << 20));   // [50000,128] bf16 = 12.8 MB
    uint*   aggb   = (uint*)(ws + (size_t)28 * (1 << 20));   // [50000,128] bf16 = 12.8 MB

    hipMemsetAsync(ws, 0, (size_t)1 << 20, stream);  // deg + flags

    k_pre  <<<(T_CAB + 255) / 256, 256, 0, stream>>>(x, xb, dst, deg,
                                                     W1l, W1r, Bp1,
                                                     W2l, W2r, Wlin, b2l, pq, cab);
    k_scan <<<NB_SCAN, 1024, 0, stream>>>(deg, bsum, flags, rowptr, cursor);
    k_fill <<<FILL_CHUNKS * NPART, 256, 0, stream>>>(src, dst, cursor, ssrc);
    k_agg1 <<<NN / 4, 256, 0, stream>>>(xb, aggb, rowptr, ssrc);
    k_gemm1<<<(NN + 63) / 64, 256, 0, stream>>>(aggb, xb, Bp1, b1l, pq, g2, u2);
    k_sagg <<<(NN + 255) / 256, 256, 0, stream>>>(g2, u2, rowptr, ssrc, cab, sa, sb);
    k_pairs<<<(NP + 255) / 256, 256, 0, stream>>>(sa, sb, mask, blin, out);
}

// Round 6
// 214.703 us; speedup vs baseline: 1.0268x; 1.0268x over previous
//
#include <hip/hip_runtime.h>
#include <math.h>

#define NN 50000
#define NE 600000
#define NP 200000
#define NB_SCAN 49  // ceil(NN / 1024)

typedef unsigned int uint;
typedef unsigned short ushort;
typedef __attribute__((ext_vector_type(8))) short bf16x8;
typedef __attribute__((ext_vector_type(4))) float f32x4;

// ---- bf16 helpers (RNE) ----
__device__ __forceinline__ ushort f2bf(float f) {
    uint u = __float_as_uint(f);
    uint r = (u + 0x7FFFu + ((u >> 16) & 1u)) >> 16;
    return (ushort)r;
}
__device__ __forceinline__ float bf2f(uint lo16) {
    return __uint_as_float(lo16 << 16);
}

__device__ __forceinline__ int wave_iscan(int v, int lane) {
#pragma unroll
    for (int off = 1; off < 64; off <<= 1) {
        int t = __shfl_up(v, off, 64);
        if (lane >= off) v += t;
    }
    return v;
}

// ---- W swizzle into MFMA B-operand layout (bf16) ----
// Bp[((ct*(N/16)+nt)*64 + lane)*8 + j] = Wcat[ct*32 + (lane>>4)*8 + j][nt*16 + (lane&15)]
template <int K, int N>
__device__ __forceinline__ void prepB_one(int idx, const float* __restrict__ Wt,
                                          const float* __restrict__ Wb,
                                          ushort* __restrict__ Bp) {
    int lane = idx & 63;
    int nt = (idx >> 6) % (N / 16);
    int ct = idx / (64 * (N / 16));
    int n = nt * 16 + (lane & 15);
    int kb = ct * 32 + (lane >> 4) * 8;
#pragma unroll
    for (int j = 0; j < 8; j++) {
        int k = kb + j;
        float w = (k < K / 2) ? Wt[(size_t)k * N + n] : Wb[(size_t)(k - K / 2) * N + n];
        Bp[(size_t)idx * 8 + j] = f2bf(w);
    }
}

// ---------------- fused prologue ----------------
// ranges: x->bf16 compact (float4) | deg histogram | Bp1 swizzle | pq vectors | cab scalars
// pq[0:256]=W2l@wa, pq[256:512]=W2l@wb, pq[512:768]=W2r@wa, pq[768:1024]=W2r@wb
#define T_PREP (NN * 32)
#define T_DEG  (T_PREP + NE)
#define T_B1   (T_DEG + 8192)
#define T_PQ   (T_B1 + 1024)
#define T_CAB  (T_PQ + 2)
__global__ void k_pre(const float* __restrict__ x, uint* __restrict__ xb,
                      const int* __restrict__ dst, int* __restrict__ deg,
                      const float* __restrict__ W1l, const float* __restrict__ W1r,
                      ushort* __restrict__ Bp1,
                      const float* __restrict__ W2l, const float* __restrict__ W2r,
                      const float* __restrict__ Wlin, const float* __restrict__ b2l,
                      float* __restrict__ pq, float* __restrict__ cab) {
    int t = blockIdx.x * 256 + threadIdx.x;
    if (t < T_PREP) {
        int n = t >> 5, c4 = t & 31;
        float4 v = *(const float4*)(x + (size_t)n * 128 + c4 * 4);
        uint2 o;
        o.x = (uint)f2bf(v.x) | ((uint)f2bf(v.y) << 16);
        o.y = (uint)f2bf(v.z) | ((uint)f2bf(v.w) << 16);
        *(uint2*)(xb + (size_t)n * 64 + c4 * 2) = o;  // compact bf16 x rows (256 B)
    } else if (t < T_DEG) {
        atomicAdd(deg + dst[t - T_PREP], 1);
    } else if (t < T_B1) {
        prepB_one<256, 256>(t - T_DEG, W1l, W1r, Bp1);
    } else if (t < T_PQ) {
        int idx = t - T_B1;
        int vec = idx >> 8;          // 0..3
        int k = idx & 255;
        const float* W = (vec < 2) ? W2l : W2r;    // [256,128]
        const float* wl = Wlin + (vec & 1) * 128;  // wa or wb
        float s = 0.f;
#pragma unroll 4
        for (int j = 0; j < 128; j++) s += W[(size_t)k * 128 + j] * wl[j];
        pq[idx] = s;
    } else if (t < T_CAB) {
        int i = t - T_PQ;
        float s = 0.f;
        for (int j = 0; j < 128; j++) s += b2l[j] * Wlin[i * 128 + j];
        cab[i] = s;
    }
}

// ---------------- fused scan (phases 1+2+3, one launch, 49 co-resident blocks) --------
// Block-local scan in registers, grid barrier, then each block adds the prefix of the
// per-block sums. Fill is NOT fused: it is latency-bound scatter and needs full TLP.
__global__ __launch_bounds__(1024) void k_scan(const int* __restrict__ deg,
                                               int* __restrict__ bsum,
                                               int* __restrict__ flags,
                                               int* __restrict__ rowptr,
                                               int* __restrict__ cursor) {
    int tid = threadIdx.x;
    int i = blockIdx.x * 1024 + tid;
    int lane = tid & 63, wid = tid >> 6;
    int v = (i < NN) ? deg[i] : 0;
    int incl = wave_iscan(v, lane);
    __shared__ int wt[16];
    __shared__ int sboff;
    if (lane == 63) wt[wid] = incl;
    __syncthreads();
    if (tid < 16) {
        int w = wt[tid];
#pragma unroll
        for (int off = 1; off < 16; off <<= 1) {
            int t = __shfl_up(w, off, 64);
            if (tid >= off) w += t;
        }
        wt[tid] = w;
    }
    __syncthreads();
    int base = (wid > 0) ? wt[wid - 1] : 0;
    int excl_local = incl - v + base;  // exclusive within block (register only)
    if (tid == 0)
        __hip_atomic_store(&bsum[blockIdx.x], wt[15], __ATOMIC_RELEASE,
                           __HIP_MEMORY_SCOPE_AGENT);
    // ---- grid barrier ----
    __syncthreads();
    if (tid == 0) {
        __hip_atomic_fetch_add(&flags[0], 1, __ATOMIC_ACQ_REL, __HIP_MEMORY_SCOPE_AGENT);
        while (__hip_atomic_load(&flags[0], __ATOMIC_ACQUIRE,
                                 __HIP_MEMORY_SCOPE_AGENT) < NB_SCAN) {}
    }
    __syncthreads();
    // ---- block offset = sum of bsum for blocks before me ----
    if (tid < 64) {
        int b = (tid < NB_SCAN && tid < (int)blockIdx.x)
                    ? __hip_atomic_load(&bsum[tid], __ATOMIC_ACQUIRE,
                                        __HIP_MEMORY_SCOPE_AGENT)
                    : 0;
#pragma unroll
        for (int off = 1; off < 64; off <<= 1) b += __shfl_xor(b, off, 64);
        if (tid == 0) sboff = b;
    }
    __syncthreads();
    int boff = sboff;
    if (i < NN) {
        int rv = excl_local + boff;
        rowptr[i] = rv;
        cursor[i] = rv;
    }
    if (i == 0) rowptr[NN] = NE;
}

// ---------------- edge placement at full TLP: 4 edges/thread, int4 loads --------------
__global__ void k_fill(const int* __restrict__ src, const int* __restrict__ dst,
                       int* __restrict__ cursor, int* __restrict__ ssrc) {
    int e0 = (blockIdx.x * 256 + threadIdx.x) * 4;
    if (e0 >= NE) return;
    int4 d4 = *(const int4*)(dst + e0);
    int4 s4 = *(const int4*)(src + e0);
    int p0 = atomicAdd(cursor + d4.x, 1);
    int p1 = atomicAdd(cursor + d4.y, 1);
    int p2 = atomicAdd(cursor + d4.z, 1);
    int p3 = atomicAdd(cursor + d4.w, 1);
    ssrc[p0] = s4.x;
    ssrc[p1] = s4.y;
    ssrc[p2] = s4.z;
    ssrc[p3] = s4.w;
}

// ---------------- gather-mean of x(bf16) -> agg (compact) -----------------------------
// Wave per node (max TLP for the latency-bound random gather); 16 lanes x uint4 per row
// -> 4 edges per wave-load (1 KB/instr), 2 loads in flight (8 edges).
__global__ void k_agg1(const uint* __restrict__ xb, uint* __restrict__ aggb,
                       const int* __restrict__ rowptr, const int* __restrict__ ssrc) {
    int t = blockIdx.x * 256 + threadIdx.x;
    int n = t >> 6;
    if (n >= NN) return;
    int lane = t & 63;
    int g = lane >> 4;      // edge group 0..3
    int s = lane & 15;      // 16-byte chunk within row (cols 8s..8s+7)
    int r0 = rowptr[n], r1 = rowptr[n + 1];
    float a0[8] = {0.f, 0.f, 0.f, 0.f, 0.f, 0.f, 0.f, 0.f};
    float a1[8] = {0.f, 0.f, 0.f, 0.f, 0.f, 0.f, 0.f, 0.f};
    int e = r0;
    for (; e + 8 <= r1; e += 8) {
        int sA = ssrc[e + g];
        int sB = ssrc[e + 4 + g];
        uint4 vA = *(const uint4*)(xb + (size_t)sA * 64 + s * 4);
        uint4 vB = *(const uint4*)(xb + (size_t)sB * 64 + s * 4);
        a0[0] += bf2f(vA.x & 0xffffu); a0[1] += bf2f(vA.x >> 16);
        a0[2] += bf2f(vA.y & 0xffffu); a0[3] += bf2f(vA.y >> 16);
        a0[4] += bf2f(vA.z & 0xffffu); a0[5] += bf2f(vA.z >> 16);
        a0[6] += bf2f(vA.w & 0xffffu); a0[7] += bf2f(vA.w >> 16);
        a1[0] += bf2f(vB.x & 0xffffu); a1[1] += bf2f(vB.x >> 16);
        a1[2] += bf2f(vB.y & 0xffffu); a1[3] += bf2f(vB.y >> 16);
        a1[4] += bf2f(vB.z & 0xffffu); a1[5] += bf2f(vB.z >> 16);
        a1[6] += bf2f(vB.w & 0xffffu); a1[7] += bf2f(vB.w >> 16);
    }
    if (e + 4 <= r1) {
        int sA = ssrc[e + g];
        uint4 vA = *(const uint4*)(xb + (size_t)sA * 64 + s * 4);
        a0[0] += bf2f(vA.x & 0xffffu); a0[1] += bf2f(vA.x >> 16);
        a0[2] += bf2f(vA.y & 0xffffu); a0[3] += bf2f(vA.y >> 16);
        a0[4] += bf2f(vA.z & 0xffffu); a0[5] += bf2f(vA.z >> 16);
        a0[6] += bf2f(vA.w & 0xffffu); a0[7] += bf2f(vA.w >> 16);
        e += 4;
    }
    int rem = r1 - e;  // 0..3
    if (g < rem) {
        int sB = ssrc[e + g];
        uint4 vB = *(const uint4*)(xb + (size_t)sB * 64 + s * 4);
        a1[0] += bf2f(vB.x & 0xffffu); a1[1] += bf2f(vB.x >> 16);
        a1[2] += bf2f(vB.y & 0xffffu); a1[3] += bf2f(vB.y >> 16);
        a1[4] += bf2f(vB.z & 0xffffu); a1[5] += bf2f(vB.z >> 16);
        a1[6] += bf2f(vB.w & 0xffffu); a1[7] += bf2f(vB.w >> 16);
    }
    float ax[8];
#pragma unroll
    for (int j = 0; j < 8; j++) ax[j] = a0[j] + a1[j];
    // fold the 4 edge-groups (lanes differing in bits 4,5 hold same cols)
#pragma unroll
    for (int j = 0; j < 8; j++) {
        ax[j] += __shfl_xor(ax[j], 16, 64);
        ax[j] += __shfl_xor(ax[j], 32, 64);
    }
    if (g == 0) {
        float sc = 1.0f / fmaxf((float)(r1 - r0), 1.0f);
        uint4 o;
        o.x = (uint)f2bf(ax[0] * sc) | ((uint)f2bf(ax[1] * sc) << 16);
        o.y = (uint)f2bf(ax[2] * sc) | ((uint)f2bf(ax[3] * sc) << 16);
        o.z = (uint)f2bf(ax[4] * sc) | ((uint)f2bf(ax[5] * sc) << 16);
        o.w = (uint)f2bf(ax[6] * sc) | ((uint)f2bf(ax[7] * sc) << 16);
        *(uint4*)(aggb + (size_t)n * 64 + s * 4) = o;
    }
}

// ---------------- layer-1 GEMM + fused layer-2 projection -----------------------------
// h1 = relu([agg|x]@[W1l;W1r]+b1l) lives only in registers. A-fragments come from the
// two compact bf16 buffers: agg (K-cols 0..127) and xb (K-cols 128..255).
// Block = 4 waves x (32 rows x 256 cols); wave owns 64 cols, 2 row-tiles.
// Layouts (m89/m91-verified): A-frag A[m=lane&15][k=quad*8+j]; C/D col=lane&15, row=quad*4+reg.
__global__ __launch_bounds__(256) void k_gemm1(const ushort* __restrict__ agg,
                                               const ushort* __restrict__ xbu,
                                               const ushort* __restrict__ Bp,
                                               const float* __restrict__ bias,
                                               const float* __restrict__ pq,
                                               float2* __restrict__ g2,
                                               float2* __restrict__ u2) {
    const int NTW = 4;
    int wave = threadIdx.x >> 6;
    int lane = threadIdx.x & 63;
    int quad = lane >> 4;
    int l15 = lane & 15;
    int mbase = blockIdx.x * 32;
    int r0 = mbase + l15;       if (r0 >= NN) r0 = NN - 1;
    int r1 = mbase + 16 + l15;  if (r1 >= NN) r1 = NN - 1;
    f32x4 acc0[NTW], acc1[NTW];
#pragma unroll
    for (int i = 0; i < NTW; i++) {
        acc0[i] = (f32x4){0.f, 0.f, 0.f, 0.f};
        acc1[i] = (f32x4){0.f, 0.f, 0.f, 0.f};
    }
    const bf16x8* bp = (const bf16x8*)Bp;
#pragma unroll
    for (int ct = 0; ct < 8; ct++) {
        const ushort* Asrc = (ct < 4) ? agg : xbu;
        int kc = (ct & 3) * 32 + quad * 8;
        bf16x8 a0 = *(const bf16x8*)(Asrc + (size_t)r0 * 128 + kc);
        bf16x8 a1 = *(const bf16x8*)(Asrc + (size_t)r1 * 128 + kc);
#pragma unroll
        for (int ntl = 0; ntl < NTW; ntl++) {
            int nt = wave * NTW + ntl;
            bf16x8 b = bp[(ct * 16 + nt) * 64 + lane];
            acc0[ntl] = __builtin_amdgcn_mfma_f32_16x16x32_bf16(a0, b, acc0[ntl], 0, 0, 0);
            acc1[ntl] = __builtin_amdgcn_mfma_f32_16x16x32_bf16(a1, b, acc1[ntl], 0, 0, 0);
        }
    }
    // epilogue: relu + project onto pq
    float pga[2][4] = {{0,0,0,0},{0,0,0,0}}, pgb[2][4] = {{0,0,0,0},{0,0,0,0}};
    float pua[2][4] = {{0,0,0,0},{0,0,0,0}}, pub[2][4] = {{0,0,0,0},{0,0,0,0}};
#pragma unroll
    for (int ntl = 0; ntl < NTW; ntl++) {
        int col = (wave * NTW + ntl) * 16 + l15;
        float bv = bias[col];
        float wpa = pq[col], wpb = pq[256 + col];
        float wqa = pq[512 + col], wqb = pq[768 + col];
#pragma unroll
        for (int reg = 0; reg < 4; reg++) {
            float v0 = acc0[ntl][reg] + bv;  v0 = v0 > 0.f ? v0 : 0.f;
            float v1 = acc1[ntl][reg] + bv;  v1 = v1 > 0.f ? v1 : 0.f;
            pga[0][reg] += v0 * wpa;  pgb[0][reg] += v0 * wpb;
            pua[0][reg] += v0 * wqa;  pub[0][reg] += v0 * wqb;
            pga[1][reg] += v1 * wpa;  pgb[1][reg] += v1 * wpb;
            pua[1][reg] += v1 * wqa;  pub[1][reg] += v1 * wqb;
        }
    }
#pragma unroll
    for (int off = 1; off < 16; off <<= 1) {
#pragma unroll
        for (int rt = 0; rt < 2; rt++) {
#pragma unroll
            for (int reg = 0; reg < 4; reg++) {
                pga[rt][reg] += __shfl_xor(pga[rt][reg], off, 64);
                pgb[rt][reg] += __shfl_xor(pgb[rt][reg], off, 64);
                pua[rt][reg] += __shfl_xor(pua[rt][reg], off, 64);
                pub[rt][reg] += __shfl_xor(pub[rt][reg], off, 64);
            }
        }
    }
    __shared__ float red[4][4][32];
    if (l15 == 0) {
#pragma unroll
        for (int rt = 0; rt < 2; rt++) {
#pragma unroll
            for (int reg = 0; reg < 4; reg++) {
                int row = rt * 16 + quad * 4 + reg;
                red[0][wave][row] = pga[rt][reg];
                red[1][wave][row] = pgb[rt][reg];
                red[2][wave][row] = pua[rt][reg];
                red[3][wave][row] = pub[rt][reg];
            }
        }
    }
    __syncthreads();
    if (threadIdx.x < 32) {
        int row = threadIdx.x;
        int m = mbase + row;
        if (m < NN) {
            float ga = (red[0][0][row] + red[0][1][row]) + (red[0][2][row] + red[0][3][row]);
            float gb = (red[1][0][row] + red[1][1][row]) + (red[1][2][row] + red[1][3][row]);
            float ua = (red[2][0][row] + red[2][1][row]) + (red[2][2][row] + red[2][3][row]);
            float ub = (red[3][0][row] + red[3][1][row]) + (red[3][2][row] + red[3][3][row]);
            g2[m] = make_float2(ga, gb);
            u2[m] = make_float2(ua, ub);
        }
    }
}

// ---------------- scalar gather-mean + final add: sa/sb per node ----------------------
__global__ void k_sagg(const float2* __restrict__ g2, const float2* __restrict__ u2,
                       const int* __restrict__ rowptr, const int* __restrict__ ssrc,
                       const float* __restrict__ cab,
                       float* __restrict__ sa, float* __restrict__ sb) {
    int n = blockIdx.x * 256 + threadIdx.x;
    if (n >= NN) return;
    int r0 = rowptr[n], r1 = rowptr[n + 1];
    float a0 = 0.f, b0 = 0.f, a1 = 0.f, b1 = 0.f;
    float a2 = 0.f, b2 = 0.f, a3 = 0.f, b3 = 0.f;
    int e = r0;
    for (; e + 4 <= r1; e += 4) {
        float2 v0 = g2[ssrc[e]];
        float2 v1 = g2[ssrc[e + 1]];
        float2 v2 = g2[ssrc[e + 2]];
        float2 v3 = g2[ssrc[e + 3]];
        a0 += v0.x; b0 += v0.y;
        a1 += v1.x; b1 += v1.y;
        a2 += v2.x; b2 += v2.y;
        a3 += v3.x; b3 += v3.y;
    }
    for (; e < r1; e++) {
        float2 v = g2[ssrc[e]];
        a0 += v.x; b0 += v.y;
    }
    float sc = 1.0f / fmaxf((float)(r1 - r0), 1.0f);
    float2 u = u2[n];
    sa[n] = ((a0 + a1) + (a2 + a3)) * sc + u.x + cab[0];
    sb[n] = ((b0 + b1) + (b2 + b3)) * sc + u.y + cab[1];
}

// ---------------- pair scorer: out[p] = sigmoid(sa[a] + sb[b] + blin) ----------------
__global__ void k_pairs(const float* __restrict__ sa, const float* __restrict__ sb,
                        const int* __restrict__ mask, const float* __restrict__ blin,
                        float* __restrict__ out) {
    int p = blockIdx.x * 256 + threadIdx.x;
    if (p >= NP) return;
    int2 m = ((const int2*)mask)[p];
    float v = sa[m.x] + sb[m.y] + blin[0];
    out[p] = 1.0f / (1.0f + __expf(-v));
}

extern "C" void kernel_launch(void* const* d_in, const int* in_sizes, int n_in,
                              void* d_out, int out_size, void* d_ws, size_t ws_size,
                              hipStream_t stream) {
    const float* x    = (const float*)d_in[0];   // [50000,128]
    const int*   ei   = (const int*)  d_in[1];   // [2,600000]
    const int*   mask = (const int*)  d_in[2];   // [200000,2]
    const float* W1l  = (const float*)d_in[3];   // [128,256]
    const float* b1l  = (const float*)d_in[4];   // [256]
    const float* W1r  = (const float*)d_in[5];   // [128,256]
    const float* W2l  = (const float*)d_in[6];   // [256,128]
    const float* b2l  = (const float*)d_in[7];   // [128]
    const float* W2r  = (const float*)d_in[8];   // [256,128]
    const float* Wlin = (const float*)d_in[9];   // [256,1]
    const float* blin = (const float*)d_in[10];  // [1]
    float* out = (float*)d_out;                  // [200000,1]

    const int* src = ei;
    const int* dst = ei + NE;

    char* ws = (char*)d_ws;
    int*    deg    = (int*)(ws);                             // 200 KB
    int*    flags  = (int*)(ws + 0xF0000);                   // 2 ints, zeroed w/ deg
    int*    rowptr = (int*)(ws + (size_t)1 * (1 << 20));
    int*    cursor = (int*)(ws + (size_t)2 * (1 << 20));
    int*    ssrc   = (int*)(ws + (size_t)3 * (1 << 20));     // 2.4 MB
    int*    bsum   = (int*)(ws + (size_t)6 * (1 << 20));     // 196 B
    ushort* Bp1    = (ushort*)(ws + (size_t)8 * (1 << 20));  // 128 KB
    float*  pq     = (float*)(ws + (size_t)9 * (1 << 20));   // 4 KB
    float*  cab    = (float*)(ws + (size_t)9 * (1 << 20) + 65536);
    float*  sa     = (float*)(ws + (size_t)10 * (1 << 20));  // 200 KB
    float*  sb     = (float*)(ws + (size_t)11 * (1 << 20));  // 200 KB
    float2* g2     = (float2*)(ws + (size_t)12 * (1 << 20)); // 400 KB
    float2* u2     = (float2*)(ws + (size_t)13 * (1 << 20)); // 400 KB
    uint*   xb     = (uint*)(ws + (size_t)14 * (1 << 20));   // [50000,128] bf16 = 12.8 MB
    uint*   aggb   = (uint*)(ws + (size_t)28 * (1 << 20));   // [50000,128] bf16 = 12.8 MB

    hipMemsetAsync(ws, 0, (size_t)1 << 20, stream);  // deg + flags

    k_pre  <<<(T_CAB + 255) / 256, 256, 0, stream>>>(x, xb, dst, deg,
                                                     W1l, W1r, Bp1,
                                                     W2l, W2r, Wlin, b2l, pq, cab);
    k_scan <<<NB_SCAN, 1024, 0, stream>>>(deg, bsum, flags, rowptr, cursor);
    k_fill <<<(NE / 4 + 255) / 256, 256, 0, stream>>>(src, dst, cursor, ssrc);
    k_agg1 <<<NN / 4, 256, 0, stream>>>(xb, aggb, rowptr, ssrc);
    k_gemm1<<<(NN + 31) / 32, 256, 0, stream>>>((const ushort*)aggb,
                                                (const ushort*)xb, Bp1, b1l,
                                                pq, g2, u2);
    k_sagg <<<(NN + 255) / 256, 256, 0, stream>>>(g2, u2, rowptr, ssrc, cab, sa, sb);
    k_pairs<<<(NP + 255) / 256, 256, 0, stream>>>(sa, sb, mask, blin, out);
}